// Round 1
// baseline (668.008 us; speedup 1.0000x reference)
//
#include <hip/hip_runtime.h>

#define NB   64
#define NH   8
#define NM   1024
#define NC   128
#define NMID 64
#define TM   64     // kf rows staged per tile (32 KB LDS)
#define NT   256    // threads per block (4 waves)

__global__ __launch_bounds__(NT, 2)
void scatt_kernel(const float* __restrict__ query,
                  const float* __restrict__ key_feat,
                  const int*   __restrict__ att_mask,
                  const float* __restrict__ value1,
                  const float* __restrict__ value2,
                  const float* __restrict__ w_basic,
                  const float* __restrict__ b_basic,
                  const float* __restrict__ w_last,
                  const float* __restrict__ b_last,
                  const float* __restrict__ w_last2,
                  const float* __restrict__ b_last2,
                  float* __restrict__ out)
{
    const int bh   = blockIdx.x;      // 0..511
    const int b    = bh >> 3;
    const int h    = bh & 7;
    const int t    = threadIdx.x;
    const int lane = t & 63;
    const int w    = t >> 6;          // wave id 0..3
    const int io   = lane >> 5;       // i-half: 0 -> i in [0,64), 1 -> [64,128)
    const int op   = lane & 31;       // o-pair index
    const int o0   = 2 * op;
    const int o1   = 2 * op + 1;

    __shared__ float kf_tile[TM * NC];   // 32 KB
    __shared__ float q_lds[NC];
    __shared__ float mlds[NM];           // mask as float, 4 KB
    __shared__ float logits[NM];         // logits -> unnormalized alpha, 4 KB
    __shared__ float poolp[4][NMID];     // per-wave pool partials
    __shared__ float pool_s[NMID];
    __shared__ float v2part[8][NC];      // v2 partials, 4 KB
    __shared__ float red[8];
    __shared__ float sscal[4];           // [0]=max logit, [1]=sum exp, [2]=mask count

    const float* kf  = key_feat + (size_t)bh * NM * NC;
    const float* v2g = value2   + (size_t)bh * NM * NC;

    if (t < NC) q_lds[t] = query[bh * NC + t];
    for (int m = t; m < NM; m += NT) mlds[m] = (float)att_mask[b * NM + m];
    __syncthreads();

    // rw registers: q folded into w_basic. 2 o's x 64 i's per thread.
    float rw0[64], rw1[64];
    {
        const float* wb = w_basic + (size_t)h * NC * NMID;
        #pragma unroll
        for (int j = 0; j < 64; ++j) {
            const int i = io * 64 + j;
            const float2 wv = *(const float2*)(wb + (size_t)i * NMID + o0);
            const float qv = q_lds[i];
            rw0[j] = qv * wv.x;
            rw1[j] = qv * wv.y;
        }
    }
    const float bb0 = b_basic[h * NMID + o0];
    const float bb1 = b_basic[h * NMID + o1];
    const float wl0 = w_last[h * NMID + o0];
    const float wl1 = w_last[h * NMID + o1];
    const float bl  = b_last[h];

    float pool0 = 0.f, pool1 = 0.f;

    // ---- Phase 1: stream key_feat, compute pool partials + logits ----
    float4 st[8];
    const float4* kf4 = (const float4*)kf;
    #pragma unroll
    for (int r = 0; r < 8; ++r) st[r] = kf4[r * NT + t];

    const int NTILES = NM / TM;   // 16
    for (int tile = 0; tile < NTILES; ++tile) {
        __syncthreads();                       // previous compute done reading kf_tile
        #pragma unroll
        for (int r = 0; r < 8; ++r) ((float4*)kf_tile)[r * NT + t] = st[r];
        if (tile + 1 < NTILES) {
            #pragma unroll
            for (int r = 0; r < 8; ++r)        // prefetch next tile; stays in flight during compute
                st[r] = kf4[(size_t)(tile + 1) * (TM * NC / 4) + r * NT + t];
        }
        __syncthreads();                       // kf_tile visible

        #pragma unroll 1
        for (int k = 0; k < TM / 4; ++k) {
            const int mm = 4 * k + w;          // wave-uniform row
            const float4* row = (const float4*)&kf_tile[mm * NC + io * 64];
            float y0a = 0.f, y0b = 0.f, y1a = 0.f, y1b = 0.f;
            #pragma unroll
            for (int j = 0; j < 8; ++j) {
                const float4 kv = row[j];
                const float4 kw = row[j + 8];
                y0a = fmaf(kv.x, rw0[4*j+0], y0a);
                y1a = fmaf(kv.x, rw1[4*j+0], y1a);
                y0a = fmaf(kv.y, rw0[4*j+1], y0a);
                y1a = fmaf(kv.y, rw1[4*j+1], y1a);
                y0a = fmaf(kv.z, rw0[4*j+2], y0a);
                y1a = fmaf(kv.z, rw1[4*j+2], y1a);
                y0a = fmaf(kv.w, rw0[4*j+3], y0a);
                y1a = fmaf(kv.w, rw1[4*j+3], y1a);
                y0b = fmaf(kw.x, rw0[4*j+32], y0b);
                y1b = fmaf(kw.x, rw1[4*j+32], y1b);
                y0b = fmaf(kw.y, rw0[4*j+33], y0b);
                y1b = fmaf(kw.y, rw1[4*j+33], y1b);
                y0b = fmaf(kw.z, rw0[4*j+34], y0b);
                y1b = fmaf(kw.z, rw1[4*j+34], y1b);
                y0b = fmaf(kw.w, rw0[4*j+35], y0b);
                y1b = fmaf(kw.w, rw1[4*j+35], y1b);
            }
            float y0 = y0a + y0b;
            float y1 = y1a + y1b;
            // combine the two i-halves (lane l <-> l^32); result identical on both halves
            y0 += __shfl_xor(y0, 32, 64);
            y1 += __shfl_xor(y1, 32, 64);
            y0 = fmaxf(y0 + bb0, 0.f);
            y1 = fmaxf(y1 + bb1, 0.f);
            const int m = tile * TM + mm;
            const float mv = mlds[m];
            pool0 = fmaf(y0, mv, pool0);
            pool1 = fmaf(y1, mv, pool1);
            // logit: sum over all 64 o = reduce (y0*wl0 + y1*wl1) over 32 o-pairs
            float c = fmaf(y0, wl0, y1 * wl1);
            #pragma unroll
            for (int s = 16; s > 0; s >>= 1) c += __shfl_down(c, s, 32);
            if (lane == 0) logits[m] = (mv != 0.f) ? (c + bl) : -1e9f;
        }
    }
    if (lane < 32) { poolp[w][o0] = pool0; poolp[w][o1] = pool1; }
    __syncthreads();   // B1

    // ---- Phase 2: masked softmax over logits + mask count + pool finalize ----
    float lmax = -1e30f, csum = 0.f;
    for (int m = t; m < NM; m += NT) { lmax = fmaxf(lmax, logits[m]); csum += mlds[m]; }
    #pragma unroll
    for (int s = 32; s > 0; s >>= 1) {
        lmax = fmaxf(lmax, __shfl_xor(lmax, s, 64));
        csum += __shfl_xor(csum, s, 64);
    }
    if (lane == 0) { red[w] = lmax; red[4 + w] = csum; }
    __syncthreads();   // B2
    if (t == 0) {
        sscal[0] = fmaxf(fmaxf(red[0], red[1]), fmaxf(red[2], red[3]));
        sscal[2] = red[4] + red[5] + red[6] + red[7];
    }
    __syncthreads();   // B3
    const float mx  = sscal[0];
    const float cnt = sscal[2];
    if (t < NMID)
        pool_s[t] = (poolp[0][t] + poolp[1][t] + poolp[2][t] + poolp[3][t]) / cnt;
    float esum = 0.f;
    for (int m = t; m < NM; m += NT) {
        const float e = __expf(logits[m] - mx);
        logits[m] = e;                 // unnormalized alpha
        esum += e;
    }
    #pragma unroll
    for (int s = 32; s > 0; s >>= 1) esum += __shfl_xor(esum, s, 64);
    if (lane == 0) red[w] = esum;      // red[0..3] safe to reuse after B3
    __syncthreads();   // B4
    if (t == 0) sscal[1] = red[0] + red[1] + red[2] + red[3];
    __syncthreads();   // B5
    const float inv_sum = 1.f / sscal[1];

    // ---- Phase 3: v2 = alpha @ value2 (streaming, unnormalized alpha) ----
    const int d4 = t & 31;     // float4 column
    const int mg = t >> 5;     // m-group 0..7
    float4 acc = make_float4(0.f, 0.f, 0.f, 0.f);
    const float4* v24 = (const float4*)v2g;
    #pragma unroll 4
    for (int m0 = 0; m0 < NM; m0 += 8) {
        const int m = m0 + mg;
        const float a = logits[m];
        const float4 v = v24[(size_t)m * 32 + d4];
        acc.x = fmaf(a, v.x, acc.x);
        acc.y = fmaf(a, v.y, acc.y);
        acc.z = fmaf(a, v.z, acc.z);
        acc.w = fmaf(a, v.w, acc.w);
    }
    ((float4*)&v2part[mg][0])[d4] = acc;
    __syncthreads();   // B6

    // ---- Phase 4: channel gate + epilogue ----
    if (t < NC) {
        float v2d = 0.f;
        #pragma unroll
        for (int g = 0; g < 8; ++g) v2d += v2part[g][t];
        v2d *= inv_sum;
        float accd = b_last2[h * NC + t];
        const float* wl2 = w_last2 + (size_t)h * NMID * NC + t;
        #pragma unroll 8
        for (int o = 0; o < NMID; ++o)
            accd = fmaf(pool_s[o], wl2[(size_t)o * NC], accd);
        const float ach = 1.f / (1.f + __expf(-accd));
        out[bh * NC + t] = value1[bh * NC + t] * v2d * ach;
    }
}

extern "C" void kernel_launch(void* const* d_in, const int* in_sizes, int n_in,
                              void* d_out, int out_size, void* d_ws, size_t ws_size,
                              hipStream_t stream) {
    const float* query    = (const float*)d_in[0];
    const float* key_feat = (const float*)d_in[1];
    const int*   att_mask = (const int*)d_in[2];
    const float* value1   = (const float*)d_in[3];
    const float* value2   = (const float*)d_in[4];
    const float* w_basic  = (const float*)d_in[5];
    const float* b_basic  = (const float*)d_in[6];
    const float* w_last   = (const float*)d_in[7];
    const float* b_last   = (const float*)d_in[8];
    const float* w_last2  = (const float*)d_in[9];
    const float* b_last2  = (const float*)d_in[10];
    float* outp = (float*)d_out;

    scatt_kernel<<<dim3(NB * NH), dim3(NT), 0, stream>>>(
        query, key_feat, att_mask, value1, value2,
        w_basic, b_basic, w_last, b_last, w_last2, b_last2, outp);
}

// Round 2
// 518.357 us; speedup vs baseline: 1.2887x; 1.2887x over previous
//
#include <hip/hip_runtime.h>

#define NB   64
#define NH   8
#define NM   1024
#define NC   128     // K (i)
#define NMID 64      // N (o)
#define NT   256     // 4 waves
#define TM   32      // kf rows per LDS tile
#define NTILES (NM / TM)   // 32
#define RWS  136     // rwT row stride (shorts)
#define KFS  136     // kf tile row stride (shorts)

typedef __attribute__((ext_vector_type(8))) short s16x8;
typedef __attribute__((ext_vector_type(4))) short s16x4;
typedef __attribute__((ext_vector_type(4))) float f32x4;

__device__ __forceinline__ short f2bf(float x) {          // RNE float->bf16 bits
    union { float f; unsigned u; } v; v.f = x;
    unsigned r = (v.u + 0x7fffu + ((v.u >> 16) & 1u)) >> 16;
    return (short)r;
}
__device__ __forceinline__ float bf2f(short s) {
    union { unsigned u; float f; } v; v.u = ((unsigned)(unsigned short)s) << 16;
    return v.f;
}

__global__ __launch_bounds__(NT, 2)
void scatt_kernel(const float* __restrict__ query,
                  const float* __restrict__ key_feat,
                  const int*   __restrict__ att_mask,
                  const float* __restrict__ value1,
                  const float* __restrict__ value2,
                  const float* __restrict__ w_basic,
                  const float* __restrict__ b_basic,
                  const float* __restrict__ w_last,
                  const float* __restrict__ b_last,
                  const float* __restrict__ w_last2,
                  const float* __restrict__ b_last2,
                  float* __restrict__ out)
{
    const int bh   = blockIdx.x;          // 0..511
    const int b    = bh >> 3;
    const int h    = bh & 7;
    const int t    = threadIdx.x;
    const int lane = t & 63;
    const int w    = t >> 6;              // wave 0..3
    const int oh   = w & 1;               // o-half: o in [oh*32, +32)
    const int rt   = w >> 1;              // row-half within 32-row tile
    const int ln15 = lane & 15;
    const int lq   = lane >> 4;           // 0..3

    // ---- LDS (65328 B total) ----
    __shared__ short rwT_hi[NMID * RWS];  // 17408 B : B^T hi, [o][i]
    __shared__ short rwT_lo[NMID * RWS];  // 17408 B
    __shared__ short kf_hi[TM * KFS];     //  8704 B : A tile hi, [m][i]
    __shared__ short kf_lo[TM * KFS];     //  8704 B
    __shared__ float logith[2][NM];       //  8192 B : per-o-half logit partials -> alpha
    __shared__ float poolp[4][32];        //   512 B
    __shared__ float pool_s[NMID];        //   256 B
    __shared__ float v2part[8][NC];       //  4096 B
    __shared__ float red[8];
    __shared__ float sscal[4];

    const float* kf  = key_feat + (size_t)bh * NM * NC;
    const float* v2g = value2   + (size_t)bh * NM * NC;

    // ---- prefetch kf tile 0 (in flight during rw build) ----
    float4 st[4];
    const float4* kf4 = (const float4*)kf;
    #pragma unroll
    for (int r = 0; r < 4; ++r) st[r] = kf4[r * NT + t];

    // ---- build rwT = (q (.) w_basic)^T as bf16 hi/lo ----
    {
        const float* wb = w_basic + (size_t)h * NC * NMID;
        const float* qp = query + bh * NC;
        #pragma unroll 4
        for (int r = 0; r < 32; ++r) {
            const int f = r * NT + t;      // = i*64 + o (coalesced over wb)
            const int o = f & 63;
            const int i = f >> 6;
            const float x = qp[i] * wb[f];
            const short hi = f2bf(x);
            rwT_hi[o * RWS + i] = hi;
            rwT_lo[o * RWS + i] = f2bf(x - bf2f(hi));
        }
    }
    __syncthreads();

    // ---- hoist B fragments (tile-invariant): 2 o-subtiles x 4 ksteps x hi/lo ----
    s16x8 Bh[2][4], Bl[2][4];
    #pragma unroll
    for (int otl = 0; otl < 2; ++otl) {
        const int o = oh * 32 + otl * 16 + ln15;
        #pragma unroll
        for (int ks = 0; ks < 4; ++ks) {
            const int off = o * RWS + ks * 32 + lq * 8;
            Bh[otl][ks] = *(const s16x8*)&rwT_hi[off];
            Bl[otl][ks] = *(const s16x8*)&rwT_lo[off];
        }
    }

    const int o_0 = oh * 32 + ln15;        // acc0 column
    const int o_1 = o_0 + 16;              // acc1 column
    const float bb0 = b_basic[h * NMID + o_0];
    const float bb1 = b_basic[h * NMID + o_1];
    const float wl0 = w_last[h * NMID + o_0];
    const float wl1 = w_last[h * NMID + o_1];
    const float bl  = b_last[h];

    float pool0 = 0.f, pool1 = 0.f;
    const int abase = (rt * 16 + ln15) * KFS + lq * 8;

    // ---- Phase 1: stream kf tiles, MFMA, fused epilogue ----
    #pragma unroll 1
    for (int tile = 0; tile < NTILES; ++tile) {
        if (tile) __syncthreads();                 // prev tile fully consumed
        #pragma unroll
        for (int r = 0; r < 4; ++r) {              // convert + stage
            const int g   = r * NT + t;            // granule (16B) index
            const int row = g >> 5;
            const int gc  = g & 31;
            const float v0 = st[r].x, v1 = st[r].y, v2 = st[r].z, v3 = st[r].w;
            s16x4 h4, l4;
            short hh;
            hh = f2bf(v0); h4[0] = hh; l4[0] = f2bf(v0 - bf2f(hh));
            hh = f2bf(v1); h4[1] = hh; l4[1] = f2bf(v1 - bf2f(hh));
            hh = f2bf(v2); h4[2] = hh; l4[2] = f2bf(v2 - bf2f(hh));
            hh = f2bf(v3); h4[3] = hh; l4[3] = f2bf(v3 - bf2f(hh));
            *(s16x4*)&kf_hi[row * KFS + gc * 4] = h4;
            *(s16x4*)&kf_lo[row * KFS + gc * 4] = l4;
        }
        __syncthreads();                           // tile visible
        if (tile + 1 < NTILES) {                   // prefetch AFTER barrier: stays in flight
            #pragma unroll
            for (int r = 0; r < 4; ++r)
                st[r] = kf4[(size_t)(tile + 1) * (TM * NC / 4) + r * NT + t];
        }

        f32x4 acc0 = {0.f, 0.f, 0.f, 0.f};
        f32x4 acc1 = {0.f, 0.f, 0.f, 0.f};
        #pragma unroll
        for (int ks = 0; ks < 4; ++ks) {
            const s16x8 Ah = *(const s16x8*)&kf_hi[abase + ks * 32];
            const s16x8 Al = *(const s16x8*)&kf_lo[abase + ks * 32];
            acc0 = __builtin_amdgcn_mfma_f32_16x16x32_bf16(Ah, Bh[0][ks], acc0, 0, 0, 0);
            acc1 = __builtin_amdgcn_mfma_f32_16x16x32_bf16(Ah, Bh[1][ks], acc1, 0, 0, 0);
            acc0 = __builtin_amdgcn_mfma_f32_16x16x32_bf16(Al, Bh[0][ks], acc0, 0, 0, 0);
            acc1 = __builtin_amdgcn_mfma_f32_16x16x32_bf16(Al, Bh[1][ks], acc1, 0, 0, 0);
            acc0 = __builtin_amdgcn_mfma_f32_16x16x32_bf16(Ah, Bl[0][ks], acc0, 0, 0, 0);
            acc1 = __builtin_amdgcn_mfma_f32_16x16x32_bf16(Ah, Bl[1][ks], acc1, 0, 0, 0);
        }

        // epilogue: relu + pool + logit partial. D layout: col=lane&15, row=(lane>>4)*4+reg
        const int mbase = tile * TM + rt * 16 + lq * 4;
        float c4[4];
        #pragma unroll
        for (int reg = 0; reg < 4; ++reg) {
            const int m = mbase + reg;
            const float mvf = (float)att_mask[b * NM + m];
            const float y0 = fmaxf(acc0[reg] + bb0, 0.f);
            const float y1 = fmaxf(acc1[reg] + bb1, 0.f);
            pool0 = fmaf(mvf, y0, pool0);
            pool1 = fmaf(mvf, y1, pool1);
            c4[reg] = fmaf(y0, wl0, y1 * wl1);
        }
        #pragma unroll
        for (int reg = 0; reg < 4; ++reg) {
            #pragma unroll
            for (int s = 1; s < 16; s <<= 1) c4[reg] += __shfl_xor(c4[reg], s, 64);
        }
        if (ln15 == 0) {
            #pragma unroll
            for (int reg = 0; reg < 4; ++reg) logith[oh][mbase + reg] = c4[reg];
        }
    }

    // pool: reduce over row-quad groups (lane>>4)
    pool0 += __shfl_xor(pool0, 16, 64); pool0 += __shfl_xor(pool0, 32, 64);
    pool1 += __shfl_xor(pool1, 16, 64); pool1 += __shfl_xor(pool1, 32, 64);
    if (lane < 16) { poolp[w][lane] = pool0; poolp[w][16 + lane] = pool1; }
    __syncthreads();   // B1

    // ---- Phase 2: combine logit halves, masked softmax prep, pool finalize ----
    float lmax = -1e30f, csum = 0.f;
    for (int m = t; m < NM; m += NT) {
        const int mv = att_mask[b * NM + m];
        float lg = logith[0][m] + logith[1][m] + bl;
        lg = mv ? lg : -1e9f;
        logith[0][m] = lg;
        lmax = fmaxf(lmax, lg);
        csum += (float)mv;
    }
    #pragma unroll
    for (int s = 32; s > 0; s >>= 1) {
        lmax = fmaxf(lmax, __shfl_xor(lmax, s, 64));
        csum += __shfl_xor(csum, s, 64);
    }
    if (lane == 0) { red[w] = lmax; red[4 + w] = csum; }
    __syncthreads();   // B2
    if (t == 0) {
        sscal[0] = fmaxf(fmaxf(red[0], red[1]), fmaxf(red[2], red[3]));
        sscal[2] = red[4] + red[5] + red[6] + red[7];
    }
    __syncthreads();   // B3
    const float mx  = sscal[0];
    const float cnt = sscal[2];
    if (t < NMID) {
        const int ohp = t >> 5, j = t & 31;
        pool_s[t] = (poolp[ohp][j] + poolp[ohp + 2][j]) / cnt;
    }
    float esum = 0.f;
    for (int m = t; m < NM; m += NT) {
        const float e = __expf(logith[0][m] - mx);
        logith[0][m] = e;               // unnormalized alpha
        esum += e;
    }
    #pragma unroll
    for (int s = 32; s > 0; s >>= 1) esum += __shfl_xor(esum, s, 64);
    if (lane == 0) red[w] = esum;
    __syncthreads();   // B4
    if (t == 0) sscal[1] = red[0] + red[1] + red[2] + red[3];
    __syncthreads();   // B5
    const float inv_sum = 1.f / sscal[1];

    // ---- Phase 3: v2 = alpha @ value2 (streaming) ----
    const int d4 = t & 31;
    const int mg = t >> 5;
    float4 acc = make_float4(0.f, 0.f, 0.f, 0.f);
    const float4* v24 = (const float4*)v2g;
    #pragma unroll 4
    for (int m0 = 0; m0 < NM; m0 += 8) {
        const int m = m0 + mg;
        const float a = logith[0][m];
        const float4 v = v24[(size_t)m * 32 + d4];
        acc.x = fmaf(a, v.x, acc.x);
        acc.y = fmaf(a, v.y, acc.y);
        acc.z = fmaf(a, v.z, acc.z);
        acc.w = fmaf(a, v.w, acc.w);
    }
    ((float4*)&v2part[mg][0])[d4] = acc;
    __syncthreads();   // B6

    // ---- Phase 4: channel gate + output ----
    if (t < NC) {
        float v2d = 0.f;
        #pragma unroll
        for (int g = 0; g < 8; ++g) v2d += v2part[g][t];
        v2d *= inv_sum;
        float accd = b_last2[h * NC + t];
        const float* wl2 = w_last2 + (size_t)h * NMID * NC + t;
        #pragma unroll 8
        for (int o = 0; o < NMID; ++o)
            accd = fmaf(pool_s[o], wl2[(size_t)o * NC], accd);
        const float ach = 1.f / (1.f + __expf(-accd));
        out[bh * NC + t] = value1[bh * NC + t] * v2d * ach;
    }
}

extern "C" void kernel_launch(void* const* d_in, const int* in_sizes, int n_in,
                              void* d_out, int out_size, void* d_ws, size_t ws_size,
                              hipStream_t stream) {
    (void)in_sizes; (void)n_in; (void)out_size; (void)d_ws; (void)ws_size;
    const float* query    = (const float*)d_in[0];
    const float* key_feat = (const float*)d_in[1];
    const int*   att_mask = (const int*)d_in[2];
    const float* value1   = (const float*)d_in[3];
    const float* value2   = (const float*)d_in[4];
    const float* w_basic  = (const float*)d_in[5];
    const float* b_basic  = (const float*)d_in[6];
    const float* w_last   = (const float*)d_in[7];
    const float* b_last   = (const float*)d_in[8];
    const float* w_last2  = (const float*)d_in[9];
    const float* b_last2  = (const float*)d_in[10];
    float* outp = (float*)d_out;

    scatt_kernel<<<dim3(NB * NH), dim3(NT), 0, stream>>>(
        query, key_feat, att_mask, value1, value2,
        w_basic, b_basic, w_last, b_last, w_last2, b_last2, outp);
}